// Round 2
// baseline (2048.733 us; speedup 1.0000x reference)
//
#include <hip/hip_runtime.h>

// ---------------- ws layout (float offsets) ----------------
// [0]        : dtype flag (int: 1 = bf16 inputs, 0 = fp32 inputs)
// O_WC       : Wc = W1 @ W_enc   [64][128] fp32
// O_BC       : bc = W1 @ b_enc   [64] fp32
// O_BIAS     : bias = b_ih+b_hh  [1024] fp32
// O_BLEND1   : blend1 [1024][50][64] fp32
// O_XW       : xw [1024][50][1024] fp32 (fp32 fallback path only)
#define O_WC     16
#define O_BC     (16 + 8192)
#define O_BIAS   (O_BC + 64)
#define O_BLEND1 16384
#define O_XW     4194304
#define XW_FLOATS 52428800ULL   // 1024*50*1024
#define NEG_INF_V (-1.0e9f)

using bf16x8 = __attribute__((ext_vector_type(8))) __bf16;
using f32x4  = __attribute__((ext_vector_type(4))) float;

__device__ __forceinline__ f32x4 mfma16(bf16x8 a, bf16x8 b, f32x4 c) {
  return __builtin_amdgcn_mfma_f32_16x16x32_bf16(a, b, c, 0, 0, 0);
}

__device__ __forceinline__ float b2f(unsigned int u) {
  union { unsigned int i; float f; } x; x.i = u << 16; return x.f;
}
__device__ __forceinline__ unsigned short f2b(float f) {
  union { float f; unsigned int i; } x; x.f = f;
  unsigned int r = x.i + 0x7fffu + ((x.i >> 16) & 1u);
  return (unsigned short)(r >> 16);
}
__device__ __forceinline__ float ldv(const void* p, int b16, long long i) {
  if (b16) return b2f(((const unsigned short*)p)[i]);
  return ((const float*)p)[i];
}
__device__ __forceinline__ float sigm(float x)  { return 1.0f / (1.0f + __expf(-x)); }
__device__ __forceinline__ float tanhx(float x) { return 1.0f - 2.0f / (1.0f + __expf(2.0f * x)); }
// XOR swizzle for the fp32 fallback path LDS layout.
__device__ __forceinline__ int SW(int j) { return j ^ ((j >> 3) & 7); }

// select bf16 element e (0..7) out of a uint4, e must be unroll-constant
__device__ __forceinline__ float bfsel(const uint4& u, int e) {
  unsigned int w = (e < 2) ? u.x : (e < 4) ? u.y : (e < 6) ? u.z : u.w;
  union { unsigned int i; float f; } x;
  x.i = (e & 1) ? (w & 0xffff0000u) : (w << 16);
  return x.f;
}
#define FMA4(A, F, H) { A.x += (F)*(H).x; A.y += (F)*(H).y; A.z += (F)*(H).z; A.w += (F)*(H).w; }

// fp32 fallback: acc 4 rows x 4 batch over NM*64 K-elems, K-slice s.
template<int NM, int LDW>
__device__ __forceinline__ void rows4_f32(
    const float* W, int row0, int s, const float (*hb)[4],
    float4& a0, float4& a1, float4& a2, float4& a3) {
  #pragma unroll 2
  for (int m = 0; m < NM; ++m) {
    const int e0 = 64 * m + 8 * s;
    #pragma unroll
    for (int e = 0; e < 8; ++e) {
      const float4 hv = *(const float4*)&hb[SW(e0 + e)][0];
      float f0 = W[(long long)(row0 + 0) * LDW + e0 + e]; FMA4(a0, f0, hv);
      float f1 = W[(long long)(row0 + 1) * LDW + e0 + e]; FMA4(a1, f1, hv);
      float f2 = W[(long long)(row0 + 2) * LDW + e0 + e]; FMA4(a2, f2, hv);
      float f3 = W[(long long)(row0 + 3) * LDW + e0 + e]; FMA4(a3, f3, hv);
    }
  }
}

// ---------------- prep0: dtype detect + bias + bc ----------------
__global__ void prep0(const void* b_enc, const void* b_ih, const void* b_hh,
                      const void* W1, float* ws) {
  __shared__ int anybig;
  int t = threadIdx.x;
  if (t == 0) anybig = 0;
  __syncthreads();
  {
    unsigned short u = ((const unsigned short*)b_enc)[t];
    float f = b2f((unsigned int)u);
    if (!(fabsf(f) <= 1.0f)) atomicOr(&anybig, 1);
  }
  __syncthreads();
  int b16 = anybig ? 0 : 1;
  if (t == 0) ((int*)ws)[0] = b16;
  for (int k = t; k < 1024; k += 256)
    ws[O_BIAS + k] = ldv(b_ih, b16, k) + ldv(b_hh, b16, k);
  if (t < 64) {
    float acc = 0.f;
    for (int h = 0; h < 256; ++h)
      acc += ldv(W1, b16, t * 256 + h) * ldv(b_enc, b16, h);
    ws[O_BC + t] = acc;
  }
}

// ---------------- prep1: Wc = W1 @ W_enc ----------------
__global__ void prep1(const void* W_enc, const void* W1, float* ws) {
  int b16 = ((const int*)ws)[0];
  int o = blockIdx.x * 256 + threadIdx.x;
  int w = o >> 7, i = o & 127;
  float acc = 0.f;
  for (int h = 0; h < 256; ++h)
    acc += ldv(W1, b16, w * 256 + h) * ldv(W_enc, b16, h * 128 + i);
  ws[O_WC + o] = acc;
}

// ---------------- blendk: blend1 = targets @ Wc^T + bc ----------------
__global__ __launch_bounds__(256) void blendk(const void* targets, float* ws) {
  __shared__ float tg[6400];
  __shared__ float wc[8192];
  int b16 = ((const int*)ws)[0];
  int t = threadIdx.x, b = blockIdx.x;
  for (int k = t; k < 8192; k += 256) wc[k] = ws[O_WC + k];
  if (b16) {
    const unsigned short* tp = (const unsigned short*)targets + (long long)b * 6400;
    for (int k = t * 8; k < 6400; k += 2048) {
      uint4 u = *(const uint4*)(tp + k);
      #pragma unroll
      for (int e = 0; e < 8; ++e) tg[k + e] = bfsel(u, e);
    }
  } else {
    const float* tp = (const float*)targets + (long long)b * 6400;
    for (int k = t; k < 6400; k += 256) tg[k] = tp[k];
  }
  __syncthreads();
  int w = t & 63, j0 = t >> 6;
  float bcv = ws[O_BC + w];
  for (int j = j0; j < 50; j += 4) {
    float acc = 0.f;
    for (int i0 = 0; i0 < 128; i0 += 8) {
      const float4* q = (const float4*)(wc + w * 128 + i0);
      float4 a = q[0], bb = q[1];
      const float* x = &tg[j * 128 + i0];
      acc += a.x * x[0] + a.y * x[1] + a.z * x[2] + a.w * x[3]
           + bb.x * x[4] + bb.y * x[5] + bb.z * x[6] + bb.w * x[7];
    }
    ws[O_BLEND1 + (b * 50 + j) * 64 + w] = acc + bcv;
  }
}

// ---------------- xwK (fp32 fallback only): xw[b][j][r] = targets[b,j,:].W_ih[r,:]
__global__ __launch_bounds__(256) void xwK(const void* targets, const void* W_ih,
                                           float* ws) {
  const int b16 = ((const int*)ws)[0];
  if (b16) return;   // bf16 path recomputes x@W_ih^T via MFMA in mainK
  __shared__ float tgl[64 * 132];
  __shared__ float wl[64 * 132];
  const int t = threadIdx.x, b = blockIdx.x;
  float* xwp = ws + O_XW + (unsigned long long)b * 51200ULL;

  const float* tp = (const float*)targets + (long long)b * 6400;
  for (int k = t; k < 6400; k += 256) tgl[(k >> 7) * 132 + (k & 127)] = tp[k];
  for (int k = t; k < 14 * 132; k += 256) tgl[50 * 132 + k] = 0.f;

  const int tr = t & 15, tj = t >> 4;
  for (int c = 0; c < 16; ++c) {
    __syncthreads();
    const float* wp = (const float*)W_ih + (long long)c * 8192;
    for (int k = t; k < 8192; k += 256) wl[(k >> 7) * 132 + (k & 127)] = wp[k];
    __syncthreads();
    float a[4][4];
    #pragma unroll
    for (int rr = 0; rr < 4; rr++)
      #pragma unroll
      for (int jj = 0; jj < 4; jj++) a[rr][jj] = 0.f;
    for (int i0 = 0; i0 < 128; i0 += 4) {
      float4 wv0 = *(const float4*)&wl[(tr + 0)  * 132 + i0];
      float4 wv1 = *(const float4*)&wl[(tr + 16) * 132 + i0];
      float4 wv2 = *(const float4*)&wl[(tr + 32) * 132 + i0];
      float4 wv3 = *(const float4*)&wl[(tr + 48) * 132 + i0];
      #pragma unroll
      for (int jj = 0; jj < 4; jj++) {
        float4 tv = *(const float4*)&tgl[(tj + 16 * jj) * 132 + i0];
        a[0][jj] += wv0.x * tv.x + wv0.y * tv.y + wv0.z * tv.z + wv0.w * tv.w;
        a[1][jj] += wv1.x * tv.x + wv1.y * tv.y + wv1.z * tv.z + wv1.w * tv.w;
        a[2][jj] += wv2.x * tv.x + wv2.y * tv.y + wv2.z * tv.z + wv2.w * tv.w;
        a[3][jj] += wv3.x * tv.x + wv3.y * tv.y + wv3.z * tv.z + wv3.w * tv.w;
      }
    }
    #pragma unroll
    for (int jj = 0; jj < 4; jj++) {
      int j = tj + 16 * jj;
      if (j < 50) {
        #pragma unroll
        for (int rr = 0; rr < 4; rr++)
          xwp[j * 1024 + c * 64 + tr + 16 * rr] = a[rr][jj];
      }
    }
  }
}

// ---------------- main: 50 sequential steps, 4 batch rows / block ----------------
// bf16 path: gates = [h_hi,h_lo]@W_hh^T + x@W_ih^T via v_mfma_f32_16x16x32_bf16.
// 1024 threads = 16 waves (4/SIMD) for latency hiding; phase A: 4 tiles/wave.
__global__ __launch_bounds__(1024) void mainK(
    const void* targets, const void* h0, const void* c0,
    const void* W_ih, const void* W_hh, const void* W2, const void* vt,
    float* ws, void* outp, int use_xw) {
  __shared__ __align__(16) float xT[128][4];               // fp32 path
  __shared__ __align__(16) float hT[256][4];               // fp32 path
  __shared__ __align__(16) unsigned short hHi[16][264];    // bf16 path (pad 8)
  __shared__ __align__(16) unsigned short hLo[16][264];
  __shared__ __align__(16) unsigned short xA[16][136];     // bf16 path (pad 8)
  __shared__ float cT[4][256];
  __shared__ float gsh[4][1024];
  __shared__ float bias_s[1024];
  __shared__ float b2s[4][64];
  __shared__ float outs[4][64];
  __shared__ float vt_s[64];
  __shared__ int   selidx[4];
  __shared__ int   selb[4][64];

  const int b16 = ((const int*)ws)[0];
  const int t = threadIdx.x;
  const int bbase = blockIdx.x * 4;
  const float* xw = ws + O_XW;

  for (int k = t; k < 1024; k += 1024) bias_s[k] = ws[O_BIAS + k];
  if (t < 64) vt_s[t] = ldv(vt, b16, t);
  if (t < 256) selb[t >> 6][t & 63] = 0;
  if (t < 4) selidx[t] = -1;

  if (b16) {
    unsigned short* z1 = &hHi[0][0];
    unsigned short* z2 = &hLo[0][0];
    unsigned short* z3 = &xA[0][0];
    for (int k = t; k < 16 * 264; k += 1024) { z1[k] = 0; z2[k] = 0; }
    for (int k = t; k < 16 * 136; k += 1024) z3[k] = 0;
    __syncthreads();
    for (int k = t; k < 1024; k += 1024) {
      int p = k >> 8, j = k & 255;
      hHi[p][j] = ((const unsigned short*)h0)[(bbase + p) * 256 + j];
      cT[p][j]  = b2f((unsigned int)((const unsigned short*)c0)[(bbase + p) * 256 + j]);
    }
  } else {
    for (int k = t; k < 1024; k += 1024) {
      int p = k & 3, j = k >> 2;
      hT[SW(j)][p] = ((const float*)h0)[(bbase + p) * 256 + j];
      cT[p][j]     = ((const float*)c0)[(bbase + p) * 256 + j];
    }
    if (t < 512) { int p = t & 3, i = t >> 2; xT[SW(i)][p] = 0.f; }
  }
  __syncthreads();

  if (b16) {
    // ================= bf16 MFMA path =================
    const int l  = t & 63, Wv = t >> 6;       // lane, wave (0..15)
    const int lr = l & 15, lg = l >> 4;
    const unsigned short* Whh = (const unsigned short*)W_hh;
    const unsigned short* Wih = (const unsigned short*)W_ih;
    const unsigned short* W2b = (const unsigned short*)W2;

    #pragma unroll 1
    for (int step = 0; step < 50; ++step) {
      // ---- phase A: gsh[p][g] = h@W_hh^T + x@W_ih^T (MFMA, 4 tiles/wave) ----
      {
        bf16x8 ahi[8], alo[8], ax[4];
        #pragma unroll
        for (int kc = 0; kc < 8; ++kc) {
          ahi[kc] = *(const bf16x8*)&hHi[lr][kc * 32 + lg * 8];
          alo[kc] = *(const bf16x8*)&hLo[lr][kc * 32 + lg * 8];
        }
        #pragma unroll
        for (int kc = 0; kc < 4; ++kc)
          ax[kc] = *(const bf16x8*)&xA[lr][kc * 32 + lg * 8];
        #pragma unroll 2
        for (int ti = 0; ti < 4; ++ti) {
          const int nt = Wv * 4 + ti;                 // gate tile (16 rows)
          const unsigned short* wh = Whh + (long long)(nt * 16 + lr) * 256 + lg * 8;
          const unsigned short* wi = Wih + (long long)(nt * 16 + lr) * 128 + lg * 8;
          // two balanced dep chains (10 / 10) instead of one 20-deep chain
          f32x4 accA = {0.f, 0.f, 0.f, 0.f};
          f32x4 accB = {0.f, 0.f, 0.f, 0.f};
          #pragma unroll
          for (int kc = 0; kc < 8; ++kc) {
            bf16x8 w = *(const bf16x8*)(wh + kc * 32);
            accA = mfma16(ahi[kc], w, accA);
            accB = mfma16(alo[kc], w, accB);
          }
          #pragma unroll
          for (int kc = 0; kc < 2; ++kc)
            accA = mfma16(ax[kc], *(const bf16x8*)(wi + kc * 32), accA);
          #pragma unroll
          for (int kc = 2; kc < 4; ++kc)
            accB = mfma16(ax[kc], *(const bf16x8*)(wi + kc * 32), accB);
          f32x4 acc = accA + accB;
          if (l < 16) {
            gsh[0][nt * 16 + l] = acc[0];
            gsh[1][nt * 16 + l] = acc[1];
            gsh[2][nt * 16 + l] = acc[2];
            gsh[3][nt * 16 + l] = acc[3];
          }
        }
      }
      __syncthreads();

      // ---- phase A2: LSTM pointwise; write h as hi+lo bf16 ----
      {
        int j = t & 255, p = t >> 8;
        float gi = sigm (gsh[p][j]       + bias_s[j]);
        float gf = sigm (gsh[p][256 + j] + bias_s[256 + j]);
        float gg = tanhx(gsh[p][512 + j] + bias_s[512 + j]);
        float go = sigm (gsh[p][768 + j] + bias_s[768 + j]);
        float c = gf * cT[p][j] + gi * gg;
        cT[p][j] = c;
        float h = go * tanhx(c);
        unsigned short hi = f2b(h);
        hHi[p][j] = hi;
        hLo[p][j] = f2b(h - b2f((unsigned int)hi));
      }
      __syncthreads();

      // ---- mini-pass: blend2 = h @ W2^T (MFMA, waves 0-3) ----
      if (Wv < 4) {
        bf16x8 bhi[8], blo[8];
        #pragma unroll
        for (int kc = 0; kc < 8; ++kc) {
          bhi[kc] = *(const bf16x8*)&hHi[lr][kc * 32 + lg * 8];
          blo[kc] = *(const bf16x8*)&hLo[lr][kc * 32 + lg * 8];
        }
        const unsigned short* wp = W2b + (long long)(Wv * 16 + lr) * 256 + lg * 8;
        f32x4 accA = {0.f, 0.f, 0.f, 0.f};
        f32x4 accB = {0.f, 0.f, 0.f, 0.f};
        #pragma unroll
        for (int kc = 0; kc < 8; ++kc) {
          bf16x8 w = *(const bf16x8*)(wp + kc * 32);
          accA = mfma16(bhi[kc], w, accA);
          accB = mfma16(blo[kc], w, accB);
        }
        f32x4 acc = accA + accB;
        if (l < 16) {
          b2s[0][Wv * 16 + l] = acc[0];
          b2s[1][Wv * 16 + l] = acc[1];
          b2s[2][Wv * 16 + l] = acc[2];
          b2s[3][Wv * 16 + l] = acc[3];
        }
      }
      __syncthreads();

      // ---- phase C: out = vt . tanh(blend1 + blend2), mask (800 thr) ----
      if (t < 800) {
        int o = t >> 2, q = t & 3;
        int p = o / 50, j = o - p * 50;
        const float* bl = ws + O_BLEND1 + (((bbase + p) * 50 + j) * 64) + q * 16;
        float acc = 0.f;
        #pragma unroll
        for (int v4 = 0; v4 < 4; ++v4) {
          float4 bv = *(const float4*)(bl + v4 * 4);
          int w0 = q * 16 + v4 * 4;
          acc += vt_s[w0 + 0] * tanhx(bv.x + b2s[p][w0 + 0]);
          acc += vt_s[w0 + 1] * tanhx(bv.y + b2s[p][w0 + 1]);
          acc += vt_s[w0 + 2] * tanhx(bv.z + b2s[p][w0 + 2]);
          acc += vt_s[w0 + 3] * tanhx(bv.w + b2s[p][w0 + 3]);
        }
        acc += __shfl_xor(acc, 1, 64);
        acc += __shfl_xor(acc, 2, 64);
        if (q == 0) outs[p][j] = selb[p][j] ? NEG_INF_V : acc;
      }
      __syncthreads();

      // ---- argmax + softmax + write probs, update selected ----
      if (t < 256) {
        int p = t >> 6, lane = t & 63;
        float v = (lane < 50) ? outs[p][lane] : -3.4e38f;
        int idx = lane;
        #pragma unroll
        for (int msk = 1; msk < 64; msk <<= 1) {
          float ov = __shfl_xor(v, msk, 64);
          int   oi = __shfl_xor(idx, msk, 64);
          if (ov > v || (ov == v && oi < idx)) { v = ov; idx = oi; }
        }
        float e = (lane < 50) ? __expf(outs[p][lane] - v) : 0.f;
        float ssum = e;
        #pragma unroll
        for (int msk = 1; msk < 64; msk <<= 1) ssum += __shfl_xor(ssum, msk, 64);
        if (lane < 50) {
          float prob = fmaxf(e / ssum, 1e-9f);
          int o = (bbase + p) * 2500 + step * 50 + lane;
          ((unsigned short*)outp)[o] = f2b(prob);
        }
        if (lane == 0) selidx[p] = idx;
        if (lane == idx) selb[p][idx] = 1;
      }
      __syncthreads();

      // ---- phase D: dec_in gather into xA (raw bf16 copy, exact) ----
      if (t < 512) {
        int p = t >> 7, i = t & 127;
        xA[p][i] = ((const unsigned short*)targets)
                       [((long long)(bbase + p) * 50 + selidx[p]) * 128 + i];
      }
      __syncthreads();
    }
    return;
  }

  // ================= fp32 fallback path (512 active threads) =================
  const int s = t & 7, G = t >> 3;

  #pragma unroll 1
  for (int step = 0; step < 50; ++step) {
    if (t < 512) {
      #pragma unroll 1
      for (int pass = 0; pass < 4; ++pass) {
        const int row0 = pass * 256 + G * 4;
        float4 a0 = {0,0,0,0}, a1 = {0,0,0,0}, a2 = {0,0,0,0}, a3 = {0,0,0,0};
        if (!use_xw)
          rows4_f32<2,128>((const float*)W_ih, row0, s, xT, a0,a1,a2,a3);
        rows4_f32<4,256>((const float*)W_hh, row0, s, hT, a0,a1,a2,a3);
        #pragma unroll
        for (int msk = 1; msk < 8; msk <<= 1) {
          a0.x += __shfl_xor(a0.x, msk, 64); a0.y += __shfl_xor(a0.y, msk, 64);
          a0.z += __shfl_xor(a0.z, msk, 64); a0.w += __shfl_xor(a0.w, msk, 64);
          a1.x += __shfl_xor(a1.x, msk, 64); a1.y += __shfl_xor(a1.y, msk, 64);
          a1.z += __shfl_xor(a1.z, msk, 64); a1.w += __shfl_xor(a1.w, msk, 64);
          a2.x += __shfl_xor(a2.x, msk, 64); a2.y += __shfl_xor(a2.y, msk, 64);
          a2.z += __shfl_xor(a2.z, msk, 64); a2.w += __shfl_xor(a2.w, msk, 64);
          a3.x += __shfl_xor(a3.x, msk, 64); a3.y += __shfl_xor(a3.y, msk, 64);
          a3.z += __shfl_xor(a3.z, msk, 64); a3.w += __shfl_xor(a3.w, msk, 64);
        }
        if (s < 4) {
          #pragma unroll
          for (int q = 0; q < 4; q++)
            if (s == q) {
              float4 aq = (q == 0) ? a0 : (q == 1) ? a1 : (q == 2) ? a2 : a3;
              gsh[0][row0 + q] = aq.x; gsh[1][row0 + q] = aq.y;
              gsh[2][row0 + q] = aq.z; gsh[3][row0 + q] = aq.w;
            }
        }
      }
    }
    __syncthreads();

    if (t < 512) {
      for (int k = t; k < 1024; k += 512) {
        int j = k & 255, p = k >> 8;
        float gi = gsh[p][j], gf = gsh[p][256 + j];
        float gg = gsh[p][512 + j], go = gsh[p][768 + j];
        if (use_xw) {
          int sv = selidx[p];
          if (sv >= 0) {
            const float* xr = xw + (((unsigned long long)(bbase + p)) * 50 + sv) * 1024ULL;
            gi += xr[j]; gf += xr[256 + j]; gg += xr[512 + j]; go += xr[768 + j];
          }
        }
        gi = sigm (gi + bias_s[j]);
        gf = sigm (gf + bias_s[256 + j]);
        gg = tanhx(gg + bias_s[512 + j]);
        go = sigm (go + bias_s[768 + j]);
        float c = gf * cT[p][j] + gi * gg;
        cT[p][j] = c;
        hT[SW(j)][p] = go * tanhx(c);
      }
    }
    __syncthreads();

    if (t < 512) {
      float4 bq = {0,0,0,0};
      const float* p0 = (const float*)W2 + G * 256;
      for (int m = 0; m < 4; ++m) {
        const int e0 = 64 * m + 8 * s;
        #pragma unroll
        for (int e = 0; e < 8; ++e) {
          const float4 hv = *(const float4*)&hT[SW(e0 + e)][0];
          float f0 = p0[e0 + e]; FMA4(bq, f0, hv);
        }
      }
      #pragma unroll
      for (int msk = 1; msk < 8; msk <<= 1) {
        bq.x += __shfl_xor(bq.x, msk, 64); bq.y += __shfl_xor(bq.y, msk, 64);
        bq.z += __shfl_xor(bq.z, msk, 64); bq.w += __shfl_xor(bq.w, msk, 64);
      }
      if (s == 0) {
        b2s[0][G] = bq.x; b2s[1][G] = bq.y; b2s[2][G] = bq.z; b2s[3][G] = bq.w;
      }
    }
    __syncthreads();

    if (t < 400) {
      int o = t >> 1, sp = t & 1;
      int p = o / 50, j = o - p * 50;
      const float* bl = ws + O_BLEND1 + (((bbase + p) * 50 + j) * 64) + sp * 32;
      float acc = 0.f;
      #pragma unroll 8
      for (int w = 0; w < 32; w++)
        acc += vt_s[sp * 32 + w] * tanhx(bl[w] + b2s[p][sp * 32 + w]);
      acc += __shfl_xor(acc, 1, 64);
      if (sp == 0) outs[p][j] = selb[p][j] ? NEG_INF_V : acc;
    }
    __syncthreads();

    if (t < 256) {
      int p = t >> 6, lane = t & 63;
      float v = (lane < 50) ? outs[p][lane] : -3.4e38f;
      int idx = lane;
      #pragma unroll
      for (int msk = 1; msk < 64; msk <<= 1) {
        float ov = __shfl_xor(v, msk, 64);
        int   oi = __shfl_xor(idx, msk, 64);
        if (ov > v || (ov == v && oi < idx)) { v = ov; idx = oi; }
      }
      float e = (lane < 50) ? __expf(outs[p][lane] - v) : 0.f;
      float ssum = e;
      #pragma unroll
      for (int msk = 1; msk < 64; msk <<= 1) ssum += __shfl_xor(ssum, msk, 64);
      if (lane < 50) {
        float prob = fmaxf(e / ssum, 1e-9f);
        int o = (bbase + p) * 2500 + step * 50 + lane;
        ((float*)outp)[o] = prob;
      }
      if (lane == 0) selidx[p] = idx;
      if (lane == idx) selb[p][idx] = 1;
    }
    __syncthreads();

    if (!use_xw) {
      if (t < 512) {
        int p = t >> 7, i = t & 127;
        xT[SW(i)][p] = ((const float*)targets)[((long long)(bbase + p) * 50 + selidx[p]) * 128 + i];
      }
      __syncthreads();
    }
  }
}

extern "C" void kernel_launch(void* const* d_in, const int* in_sizes, int n_in,
                              void* d_out, int out_size, void* d_ws, size_t ws_size,
                              hipStream_t stream) {
  (void)in_sizes; (void)n_in; (void)out_size;
  const void* targets = d_in[0];
  const void* h0      = d_in[1];
  const void* c0      = d_in[2];
  const void* W_enc   = d_in[3];
  const void* b_enc   = d_in[4];
  const void* W_ih    = d_in[5];
  const void* W_hh    = d_in[6];
  const void* b_ih    = d_in[7];
  const void* b_hh    = d_in[8];
  const void* W1      = d_in[9];
  const void* W2      = d_in[10];
  const void* vt      = d_in[11];
  float* ws = (float*)d_ws;

  int use_xw = (ws_size >= ((size_t)O_XW + (size_t)XW_FLOATS) * 4) ? 1 : 0;

  prep0<<<1, 256, 0, stream>>>(b_enc, b_ih, b_hh, W1, ws);
  prep1<<<32, 256, 0, stream>>>(W_enc, W1, ws);
  blendk<<<1024, 256, 0, stream>>>(targets, ws);
  if (use_xw) xwK<<<1024, 256, 0, stream>>>(targets, W_ih, ws);
  mainK<<<256, 1024, 0, stream>>>(targets, h0, c0, W_ih, W_hh, W2, vt, ws, d_out,
                                  use_xw);
}

// Round 3
// 1342.435 us; speedup vs baseline: 1.5261x; 1.5261x over previous
//
#include <hip/hip_runtime.h>

// ---------------- ws layout (float offsets) ----------------
// [0]        : dtype flag (int: 1 = bf16 inputs, 0 = fp32 inputs)
// O_WC       : Wc = W1 @ W_enc   [64][128] fp32
// O_BC       : bc = W1 @ b_enc   [64] fp32
// O_BIAS     : bias = b_ih+b_hh  [1024] fp32
// O_BLEND1   : blend1 [1024][50][64] fp32
// O_XW       : xw [1024][50][1024] fp32 (fp32 fallback path only)
#define O_WC     16
#define O_BC     (16 + 8192)
#define O_BIAS   (O_BC + 64)
#define O_BLEND1 16384
#define O_XW     4194304
#define XW_FLOATS 52428800ULL   // 1024*50*1024
#define NEG_INF_V (-1.0e9f)

using bf16x8 = __attribute__((ext_vector_type(8))) __bf16;
using f32x4  = __attribute__((ext_vector_type(4))) float;

__device__ __forceinline__ f32x4 mfma16(bf16x8 a, bf16x8 b, f32x4 c) {
  return __builtin_amdgcn_mfma_f32_16x16x32_bf16(a, b, c, 0, 0, 0);
}

__device__ __forceinline__ float b2f(unsigned int u) {
  union { unsigned int i; float f; } x; x.i = u << 16; return x.f;
}
__device__ __forceinline__ unsigned short f2b(float f) {
  union { float f; unsigned int i; } x; x.f = f;
  unsigned int r = x.i + 0x7fffu + ((x.i >> 16) & 1u);
  return (unsigned short)(r >> 16);
}
__device__ __forceinline__ float ldv(const void* p, int b16, long long i) {
  if (b16) return b2f(((const unsigned short*)p)[i]);
  return ((const float*)p)[i];
}
__device__ __forceinline__ float sigm(float x)  { return 1.0f / (1.0f + __expf(-x)); }
__device__ __forceinline__ float tanhx(float x) { return 1.0f - 2.0f / (1.0f + __expf(2.0f * x)); }
// XOR swizzle for the fp32 fallback path LDS layout.
__device__ __forceinline__ int SW(int j) { return j ^ ((j >> 3) & 7); }

// select bf16 element e (0..7) out of a uint4, e must be unroll-constant
__device__ __forceinline__ float bfsel(const uint4& u, int e) {
  unsigned int w = (e < 2) ? u.x : (e < 4) ? u.y : (e < 6) ? u.z : u.w;
  union { unsigned int i; float f; } x;
  x.i = (e & 1) ? (w & 0xffff0000u) : (w << 16);
  return x.f;
}
#define FMA4(A, F, H) { A.x += (F)*(H).x; A.y += (F)*(H).y; A.z += (F)*(H).z; A.w += (F)*(H).w; }

// fp32 fallback: acc 4 rows x 4 batch over NM*64 K-elems, K-slice s.
template<int NM, int LDW>
__device__ __forceinline__ void rows4_f32(
    const float* W, int row0, int s, const float (*hb)[4],
    float4& a0, float4& a1, float4& a2, float4& a3) {
  #pragma unroll 2
  for (int m = 0; m < NM; ++m) {
    const int e0 = 64 * m + 8 * s;
    #pragma unroll
    for (int e = 0; e < 8; ++e) {
      const float4 hv = *(const float4*)&hb[SW(e0 + e)][0];
      float f0 = W[(long long)(row0 + 0) * LDW + e0 + e]; FMA4(a0, f0, hv);
      float f1 = W[(long long)(row0 + 1) * LDW + e0 + e]; FMA4(a1, f1, hv);
      float f2 = W[(long long)(row0 + 2) * LDW + e0 + e]; FMA4(a2, f2, hv);
      float f3 = W[(long long)(row0 + 3) * LDW + e0 + e]; FMA4(a3, f3, hv);
    }
  }
}

// ---------------- prep0: dtype detect + bias + bc ----------------
__global__ void prep0(const void* b_enc, const void* b_ih, const void* b_hh,
                      const void* W1, float* ws) {
  __shared__ int anybig;
  int t = threadIdx.x;
  if (t == 0) anybig = 0;
  __syncthreads();
  {
    unsigned short u = ((const unsigned short*)b_enc)[t];
    float f = b2f((unsigned int)u);
    if (!(fabsf(f) <= 1.0f)) atomicOr(&anybig, 1);
  }
  __syncthreads();
  int b16 = anybig ? 0 : 1;
  if (t == 0) ((int*)ws)[0] = b16;
  for (int k = t; k < 1024; k += 256)
    ws[O_BIAS + k] = ldv(b_ih, b16, k) + ldv(b_hh, b16, k);
  if (t < 64) {
    float acc = 0.f;
    for (int h = 0; h < 256; ++h)
      acc += ldv(W1, b16, t * 256 + h) * ldv(b_enc, b16, h);
    ws[O_BC + t] = acc;
  }
}

// ---------------- prep1: Wc = W1 @ W_enc ----------------
__global__ void prep1(const void* W_enc, const void* W1, float* ws) {
  int b16 = ((const int*)ws)[0];
  int o = blockIdx.x * 256 + threadIdx.x;
  int w = o >> 7, i = o & 127;
  float acc = 0.f;
  for (int h = 0; h < 256; ++h)
    acc += ldv(W1, b16, w * 256 + h) * ldv(W_enc, b16, h * 128 + i);
  ws[O_WC + o] = acc;
}

// ---------------- blendk: blend1 = targets @ Wc^T + bc ----------------
__global__ __launch_bounds__(256) void blendk(const void* targets, float* ws) {
  __shared__ float tg[6400];
  __shared__ float wc[8192];
  int b16 = ((const int*)ws)[0];
  int t = threadIdx.x, b = blockIdx.x;
  for (int k = t; k < 8192; k += 256) wc[k] = ws[O_WC + k];
  if (b16) {
    const unsigned short* tp = (const unsigned short*)targets + (long long)b * 6400;
    for (int k = t * 8; k < 6400; k += 2048) {
      uint4 u = *(const uint4*)(tp + k);
      #pragma unroll
      for (int e = 0; e < 8; ++e) tg[k + e] = bfsel(u, e);
    }
  } else {
    const float* tp = (const float*)targets + (long long)b * 6400;
    for (int k = t; k < 6400; k += 256) tg[k] = tp[k];
  }
  __syncthreads();
  int w = t & 63, j0 = t >> 6;
  float bcv = ws[O_BC + w];
  for (int j = j0; j < 50; j += 4) {
    float acc = 0.f;
    for (int i0 = 0; i0 < 128; i0 += 8) {
      const float4* q = (const float4*)(wc + w * 128 + i0);
      float4 a = q[0], bb = q[1];
      const float* x = &tg[j * 128 + i0];
      acc += a.x * x[0] + a.y * x[1] + a.z * x[2] + a.w * x[3]
           + bb.x * x[4] + bb.y * x[5] + bb.z * x[6] + bb.w * x[7];
    }
    ws[O_BLEND1 + (b * 50 + j) * 64 + w] = acc + bcv;
  }
}

// ---------------- xwK (fp32 fallback only): xw[b][j][r] = targets[b,j,:].W_ih[r,:]
__global__ __launch_bounds__(256) void xwK(const void* targets, const void* W_ih,
                                           float* ws) {
  const int b16 = ((const int*)ws)[0];
  if (b16) return;   // bf16 path recomputes x@W_ih^T via MFMA
  __shared__ float tgl[64 * 132];
  __shared__ float wl[64 * 132];
  const int t = threadIdx.x, b = blockIdx.x;
  float* xwp = ws + O_XW + (unsigned long long)b * 51200ULL;

  const float* tp = (const float*)targets + (long long)b * 6400;
  for (int k = t; k < 6400; k += 256) tgl[(k >> 7) * 132 + (k & 127)] = tp[k];
  for (int k = t; k < 14 * 132; k += 256) tgl[50 * 132 + k] = 0.f;

  const int tr = t & 15, tj = t >> 4;
  for (int c = 0; c < 16; ++c) {
    __syncthreads();
    const float* wp = (const float*)W_ih + (long long)c * 8192;
    for (int k = t; k < 8192; k += 256) wl[(k >> 7) * 132 + (k & 127)] = wp[k];
    __syncthreads();
    float a[4][4];
    #pragma unroll
    for (int rr = 0; rr < 4; rr++)
      #pragma unroll
      for (int jj = 0; jj < 4; jj++) a[rr][jj] = 0.f;
    for (int i0 = 0; i0 < 128; i0 += 4) {
      float4 wv0 = *(const float4*)&wl[(tr + 0)  * 132 + i0];
      float4 wv1 = *(const float4*)&wl[(tr + 16) * 132 + i0];
      float4 wv2 = *(const float4*)&wl[(tr + 32) * 132 + i0];
      float4 wv3 = *(const float4*)&wl[(tr + 48) * 132 + i0];
      #pragma unroll
      for (int jj = 0; jj < 4; jj++) {
        float4 tv = *(const float4*)&tgl[(tj + 16 * jj) * 132 + i0];
        a[0][jj] += wv0.x * tv.x + wv0.y * tv.y + wv0.z * tv.z + wv0.w * tv.w;
        a[1][jj] += wv1.x * tv.x + wv1.y * tv.y + wv1.z * tv.z + wv1.w * tv.w;
        a[2][jj] += wv2.x * tv.x + wv2.y * tv.y + wv2.z * tv.z + wv2.w * tv.w;
        a[3][jj] += wv3.x * tv.x + wv3.y * tv.y + wv3.z * tv.z + wv3.w * tv.w;
      }
    }
    #pragma unroll
    for (int jj = 0; jj < 4; jj++) {
      int j = tj + 16 * jj;
      if (j < 50) {
        #pragma unroll
        for (int rr = 0; rr < 4; rr++)
          xwp[j * 1024 + c * 64 + tr + 16 * rr] = a[rr][jj];
      }
    }
  }
}

// ---------------- mainK_bf16: 8 batches/block, hi/lo fused in A rows ----------------
// A frag rows 0-7 = h_hi[batch], rows 8-15 = h_lo[batch]; one MFMA covers both.
// D rows: lanes 0-31 = hi batches 0-7, lanes 32-63 = lo batches 0-7;
// gate sum = acc + __shfl_xor(acc, 32). x (exact bf16) occupies rows 0-7 only.
// 1024 threads = 16 waves, 4 gate tiles/wave; grid = B/8 = 128.
// __launch_bounds__(1024, 4): min 4 waves/EU => 128-VGPR cap, no spill (r2 lesson).
__global__ __launch_bounds__(1024, 4) void mainK_bf16(
    const void* targets, const void* h0, const void* c0,
    const void* W_ih, const void* W_hh, const void* W2, const void* vt,
    float* ws, void* outp) {
  __shared__ __align__(16) unsigned short hS[16][264];  // rows 0-7 hi, 8-15 lo
  __shared__ __align__(16) unsigned short xA[16][136];  // rows 8-15 stay zero
  __shared__ float cT[8][256];
  __shared__ float gsh[8][1024];
  __shared__ float bias_s[1024];
  __shared__ float b2s[8][64];
  __shared__ float outs[8][64];
  __shared__ float vt_s[64];
  __shared__ int   selidx[8];
  __shared__ int   selb[8][64];
  __shared__ float pad_[4096];   // force LDS > 80 KB => 1 block/CU

  const int b16 = ((const int*)ws)[0];
  if (!b16) return;
  const int t = threadIdx.x;
  const int bbase = blockIdx.x * 8;

  pad_[t & 4095] = 0.f;
  bias_s[t] = ws[O_BIAS + t];
  if (t < 64) vt_s[t] = b2f((unsigned int)((const unsigned short*)vt)[t]);
  if (t < 512) selb[t >> 6][t & 63] = 0;
  if (t < 8) selidx[t] = -1;
  {
    unsigned short* z1 = &hS[0][0];
    unsigned short* z2 = &xA[0][0];
    for (int k = t; k < 16 * 264; k += 1024) z1[k] = 0;
    for (int k = t; k < 16 * 136; k += 1024) z2[k] = 0;
  }
  __syncthreads();
  for (int k = t; k < 2048; k += 1024) {
    int p = k >> 8, j = k & 255;
    hS[p][j] = ((const unsigned short*)h0)[(bbase + p) * 256 + j];
    cT[p][j] = b2f((unsigned int)((const unsigned short*)c0)[(bbase + p) * 256 + j]);
  }
  __syncthreads();

  const int l  = t & 63, Wv = t >> 6;   // lane, wave (0..15)
  const int lr = l & 15, lg = l >> 4;
  const unsigned short* Whh = (const unsigned short*)W_hh;
  const unsigned short* Wih = (const unsigned short*)W_ih;
  const unsigned short* W2b = (const unsigned short*)W2;

  #pragma unroll 1
  for (int step = 0; step < 50; ++step) {
    // ---- phase A: gsh[p][g] = h@W_hh^T + x@W_ih^T (MFMA, 4 tiles/wave) ----
    {
      bf16x8 ah[8], ax[4];
      #pragma unroll
      for (int kc = 0; kc < 8; ++kc)
        ah[kc] = *(const bf16x8*)&hS[lr][kc * 32 + lg * 8];
      #pragma unroll
      for (int kc = 0; kc < 4; ++kc)
        ax[kc] = *(const bf16x8*)&xA[lr][kc * 32 + lg * 8];
      #pragma unroll
      for (int ti = 0; ti < 4; ++ti) {
        const int nt = Wv * 4 + ti;                 // gate tile (16 rows)
        const unsigned short* wh = Whh + (long long)(nt * 16 + lr) * 256 + lg * 8;
        const unsigned short* wi = Wih + (long long)(nt * 16 + lr) * 128 + lg * 8;
        f32x4 acc = {0.f, 0.f, 0.f, 0.f};
        #pragma unroll
        for (int kc = 0; kc < 8; ++kc)
          acc = mfma16(ah[kc], *(const bf16x8*)(wh + kc * 32), acc);
        #pragma unroll
        for (int kc = 0; kc < 4; ++kc)
          acc = mfma16(ax[kc], *(const bf16x8*)(wi + kc * 32), acc);
        // hi (lanes 0-31) + lo (lanes 32-63)
        float s0 = acc[0] + __shfl_xor(acc[0], 32, 64);
        float s1 = acc[1] + __shfl_xor(acc[1], 32, 64);
        float s2 = acc[2] + __shfl_xor(acc[2], 32, 64);
        float s3 = acc[3] + __shfl_xor(acc[3], 32, 64);
        if (l < 32) {
          const int g = nt * 16 + (l & 15), pb = (l >> 4) * 4;
          gsh[pb + 0][g] = s0; gsh[pb + 1][g] = s1;
          gsh[pb + 2][g] = s2; gsh[pb + 3][g] = s3;
        }
      }
    }
    __syncthreads();

    // ---- phase A2: LSTM pointwise; h -> hi row p, lo row p+8 ----
    for (int k = t; k < 2048; k += 1024) {
      int j = k & 255, p = k >> 8;
      float gi = sigm (gsh[p][j]       + bias_s[j]);
      float gf = sigm (gsh[p][256 + j] + bias_s[256 + j]);
      float gg = tanhx(gsh[p][512 + j] + bias_s[512 + j]);
      float go = sigm (gsh[p][768 + j] + bias_s[768 + j]);
      float c = gf * cT[p][j] + gi * gg;
      cT[p][j] = c;
      float h = go * tanhx(c);
      unsigned short hi = f2b(h);
      hS[p][j] = hi;
      hS[p + 8][j] = f2b(h - b2f((unsigned int)hi));
    }
    __syncthreads();

    // ---- mini-pass: blend2 = h @ W2^T (MFMA, waves 0-3) ----
    if (Wv < 4) {
      bf16x8 bh[8];
      #pragma unroll
      for (int kc = 0; kc < 8; ++kc)
        bh[kc] = *(const bf16x8*)&hS[lr][kc * 32 + lg * 8];
      const unsigned short* wp = W2b + (long long)(Wv * 16 + lr) * 256 + lg * 8;
      f32x4 acc = {0.f, 0.f, 0.f, 0.f};
      #pragma unroll
      for (int kc = 0; kc < 8; ++kc)
        acc = mfma16(bh[kc], *(const bf16x8*)(wp + kc * 32), acc);
      float s0 = acc[0] + __shfl_xor(acc[0], 32, 64);
      float s1 = acc[1] + __shfl_xor(acc[1], 32, 64);
      float s2 = acc[2] + __shfl_xor(acc[2], 32, 64);
      float s3 = acc[3] + __shfl_xor(acc[3], 32, 64);
      if (l < 32) {
        const int g = Wv * 16 + (l & 15), pb = (l >> 4) * 4;
        b2s[pb + 0][g] = s0; b2s[pb + 1][g] = s1;
        b2s[pb + 2][g] = s2; b2s[pb + 3][g] = s3;
      }
    }
    __syncthreads();

    // ---- phase C: out = vt . tanh(blend1 + blend2), mask (800 thr) ----
    if (t < 800) {
      int o = t >> 1, q = t & 1;
      int p = o / 50, j = o - p * 50;
      const float* bl = ws + O_BLEND1 + (((bbase + p) * 50 + j) * 64) + q * 32;
      float acc = 0.f;
      #pragma unroll
      for (int v4 = 0; v4 < 8; ++v4) {
        float4 bv = *(const float4*)(bl + v4 * 4);
        int w0 = q * 32 + v4 * 4;
        acc += vt_s[w0 + 0] * tanhx(bv.x + b2s[p][w0 + 0]);
        acc += vt_s[w0 + 1] * tanhx(bv.y + b2s[p][w0 + 1]);
        acc += vt_s[w0 + 2] * tanhx(bv.z + b2s[p][w0 + 2]);
        acc += vt_s[w0 + 3] * tanhx(bv.w + b2s[p][w0 + 3]);
      }
      acc += __shfl_xor(acc, 1, 64);
      if (q == 0) outs[p][j] = selb[p][j] ? NEG_INF_V : acc;
    }
    __syncthreads();

    // ---- argmax + softmax + write probs, update selected (8 waves) ----
    if (t < 512) {
      int p = t >> 6, lane = t & 63;
      float v = (lane < 50) ? outs[p][lane] : -3.4e38f;
      int idx = lane;
      #pragma unroll
      for (int msk = 1; msk < 64; msk <<= 1) {
        float ov = __shfl_xor(v, msk, 64);
        int   oi = __shfl_xor(idx, msk, 64);
        if (ov > v || (ov == v && oi < idx)) { v = ov; idx = oi; }
      }
      float e = (lane < 50) ? __expf(outs[p][lane] - v) : 0.f;
      float ssum = e;
      #pragma unroll
      for (int msk = 1; msk < 64; msk <<= 1) ssum += __shfl_xor(ssum, msk, 64);
      if (lane < 50) {
        float prob = fmaxf(e / ssum, 1e-9f);
        int o = (bbase + p) * 2500 + step * 50 + lane;
        ((unsigned short*)outp)[o] = f2b(prob);
      }
      if (lane == 0) selidx[p] = idx;
      if (lane == idx) selb[p][idx] = 1;
    }
    __syncthreads();

    // ---- phase D: dec_in gather into xA rows 0-7 (raw bf16 copy, exact) ----
    {
      int p = t >> 7, i = t & 127;
      xA[p][i] = ((const unsigned short*)targets)
                     [((long long)(bbase + p) * 50 + selidx[p]) * 128 + i];
    }
    __syncthreads();
  }
}

// ---------------- mainK_f32: fp32 fallback (round-1-proven path) ----------------
__global__ __launch_bounds__(512) void mainK_f32(
    const void* targets, const void* h0, const void* c0,
    const void* W_ih, const void* W_hh, const void* W2, const void* vt,
    float* ws, void* outp, int use_xw) {
  __shared__ __align__(16) float xT[128][4];
  __shared__ __align__(16) float hT[256][4];
  __shared__ float cT[4][256];
  __shared__ float gsh[4][1024];
  __shared__ float bias_s[1024];
  __shared__ float b2s[4][64];
  __shared__ float outs[4][64];
  __shared__ float vt_s[64];
  __shared__ int   selidx[4];
  __shared__ int   selb[4][64];

  const int b16 = ((const int*)ws)[0];
  if (b16) return;
  const int t = threadIdx.x;
  const int bbase = blockIdx.x * 4;
  const float* xw = ws + O_XW;

  for (int k = t; k < 1024; k += 512) bias_s[k] = ws[O_BIAS + k];
  for (int k = t; k < 1024; k += 512) {
    int p = k & 3, j = k >> 2;
    hT[SW(j)][p] = ((const float*)h0)[(bbase + p) * 256 + j];
    cT[p][j]     = ((const float*)c0)[(bbase + p) * 256 + j];
  }
  { int p = t & 3, i = t >> 2; xT[SW(i)][p] = 0.f; }
  if (t < 64) vt_s[t] = ((const float*)vt)[t];
  if (t < 256) selb[t >> 6][t & 63] = 0;
  if (t < 4) selidx[t] = -1;
  __syncthreads();

  const int s = t & 7, G = t >> 3;

  #pragma unroll 1
  for (int step = 0; step < 50; ++step) {
    #pragma unroll 1
    for (int pass = 0; pass < 4; ++pass) {
      const int row0 = pass * 256 + G * 4;
      float4 a0 = {0,0,0,0}, a1 = {0,0,0,0}, a2 = {0,0,0,0}, a3 = {0,0,0,0};
      if (!use_xw)
        rows4_f32<2,128>((const float*)W_ih, row0, s, xT, a0,a1,a2,a3);
      rows4_f32<4,256>((const float*)W_hh, row0, s, hT, a0,a1,a2,a3);
      #pragma unroll
      for (int msk = 1; msk < 8; msk <<= 1) {
        a0.x += __shfl_xor(a0.x, msk, 64); a0.y += __shfl_xor(a0.y, msk, 64);
        a0.z += __shfl_xor(a0.z, msk, 64); a0.w += __shfl_xor(a0.w, msk, 64);
        a1.x += __shfl_xor(a1.x, msk, 64); a1.y += __shfl_xor(a1.y, msk, 64);
        a1.z += __shfl_xor(a1.z, msk, 64); a1.w += __shfl_xor(a1.w, msk, 64);
        a2.x += __shfl_xor(a2.x, msk, 64); a2.y += __shfl_xor(a2.y, msk, 64);
        a2.z += __shfl_xor(a2.z, msk, 64); a2.w += __shfl_xor(a2.w, msk, 64);
        a3.x += __shfl_xor(a3.x, msk, 64); a3.y += __shfl_xor(a3.y, msk, 64);
        a3.z += __shfl_xor(a3.z, msk, 64); a3.w += __shfl_xor(a3.w, msk, 64);
      }
      if (s < 4) {
        #pragma unroll
        for (int q = 0; q < 4; q++)
          if (s == q) {
            float4 aq = (q == 0) ? a0 : (q == 1) ? a1 : (q == 2) ? a2 : a3;
            gsh[0][row0 + q] = aq.x; gsh[1][row0 + q] = aq.y;
            gsh[2][row0 + q] = aq.z; gsh[3][row0 + q] = aq.w;
          }
      }
    }
    __syncthreads();

    for (int k = t; k < 1024; k += 512) {
      int j = k & 255, p = k >> 8;
      float gi = gsh[p][j], gf = gsh[p][256 + j];
      float gg = gsh[p][512 + j], go = gsh[p][768 + j];
      if (use_xw) {
        int sv = selidx[p];
        if (sv >= 0) {
          const float* xr = xw + (((unsigned long long)(bbase + p)) * 50 + sv) * 1024ULL;
          gi += xr[j]; gf += xr[256 + j]; gg += xr[512 + j]; go += xr[768 + j];
        }
      }
      gi = sigm (gi + bias_s[j]);
      gf = sigm (gf + bias_s[256 + j]);
      gg = tanhx(gg + bias_s[512 + j]);
      go = sigm (go + bias_s[768 + j]);
      float c = gf * cT[p][j] + gi * gg;
      cT[p][j] = c;
      hT[SW(j)][p] = go * tanhx(c);
    }
    __syncthreads();

    {
      float4 bq = {0,0,0,0};
      const float* p0 = (const float*)W2 + G * 256;
      for (int m = 0; m < 4; ++m) {
        const int e0 = 64 * m + 8 * s;
        #pragma unroll
        for (int e = 0; e < 8; ++e) {
          const float4 hv = *(const float4*)&hT[SW(e0 + e)][0];
          float f0 = p0[e0 + e]; FMA4(bq, f0, hv);
        }
      }
      #pragma unroll
      for (int msk = 1; msk < 8; msk <<= 1) {
        bq.x += __shfl_xor(bq.x, msk, 64); bq.y += __shfl_xor(bq.y, msk, 64);
        bq.z += __shfl_xor(bq.z, msk, 64); bq.w += __shfl_xor(bq.w, msk, 64);
      }
      if (s == 0) {
        b2s[0][G] = bq.x; b2s[1][G] = bq.y; b2s[2][G] = bq.z; b2s[3][G] = bq.w;
      }
    }
    __syncthreads();

    if (t < 400) {
      int o = t >> 1, sp = t & 1;
      int p = o / 50, j = o - p * 50;
      const float* bl = ws + O_BLEND1 + (((bbase + p) * 50 + j) * 64) + sp * 32;
      float acc = 0.f;
      #pragma unroll 8
      for (int w = 0; w < 32; w++)
        acc += vt_s[sp * 32 + w] * tanhx(bl[w] + b2s[p][sp * 32 + w]);
      acc += __shfl_xor(acc, 1, 64);
      if (sp == 0) outs[p][j] = selb[p][j] ? NEG_INF_V : acc;
    }
    __syncthreads();

    if (t < 256) {
      int p = t >> 6, lane = t & 63;
      float v = (lane < 50) ? outs[p][lane] : -3.4e38f;
      int idx = lane;
      #pragma unroll
      for (int msk = 1; msk < 64; msk <<= 1) {
        float ov = __shfl_xor(v, msk, 64);
        int   oi = __shfl_xor(idx, msk, 64);
        if (ov > v || (ov == v && oi < idx)) { v = ov; idx = oi; }
      }
      float e = (lane < 50) ? __expf(outs[p][lane] - v) : 0.f;
      float ssum = e;
      #pragma unroll
      for (int msk = 1; msk < 64; msk <<= 1) ssum += __shfl_xor(ssum, msk, 64);
      if (lane < 50) {
        float prob = fmaxf(e / ssum, 1e-9f);
        int o = (bbase + p) * 2500 + step * 50 + lane;
        ((float*)outp)[o] = prob;
      }
      if (lane == 0) selidx[p] = idx;
      if (lane == idx) selb[p][idx] = 1;
    }
    __syncthreads();

    if (!use_xw) {
      int p = t >> 7, i = t & 127;
      xT[SW(i)][p] = ((const float*)targets)[((long long)(bbase + p) * 50 + selidx[p]) * 128 + i];
      __syncthreads();
    }
  }
}

extern "C" void kernel_launch(void* const* d_in, const int* in_sizes, int n_in,
                              void* d_out, int out_size, void* d_ws, size_t ws_size,
                              hipStream_t stream) {
  (void)in_sizes; (void)n_in; (void)out_size;
  const void* targets = d_in[0];
  const void* h0      = d_in[1];
  const void* c0      = d_in[2];
  const void* W_enc   = d_in[3];
  const void* b_enc   = d_in[4];
  const void* W_ih    = d_in[5];
  const void* W_hh    = d_in[6];
  const void* b_ih    = d_in[7];
  const void* b_hh    = d_in[8];
  const void* W1      = d_in[9];
  const void* W2      = d_in[10];
  const void* vt      = d_in[11];
  float* ws = (float*)d_ws;

  int use_xw = (ws_size >= ((size_t)O_XW + (size_t)XW_FLOATS) * 4) ? 1 : 0;

  prep0<<<1, 256, 0, stream>>>(b_enc, b_ih, b_hh, W1, ws);
  prep1<<<32, 256, 0, stream>>>(W_enc, W1, ws);
  blendk<<<1024, 256, 0, stream>>>(targets, ws);
  if (use_xw) xwK<<<1024, 256, 0, stream>>>(targets, W_ih, ws);
  mainK_bf16<<<128, 1024, 0, stream>>>(targets, h0, c0, W_ih, W_hh, W2, vt, ws,
                                       d_out);
  mainK_f32<<<256, 512, 0, stream>>>(targets, h0, c0, W_ih, W_hh, W2, vt, ws,
                                     d_out, use_xw);
}